// Round 11
// baseline (5922.746 us; speedup 1.0000x reference)
//
#include <hip/hip_runtime.h>
#include <stdint.h>

#define NN 50000
#define NE 1600000
#define FIN 128
#define FOUT 64
#define NR 4
#define ROWS 32
#define BSH 6
#define NB 782            // ceil(NN/64)
#define CAP 4096          // bucket capacity (mean 2048, Poisson, >40 sigma)
#define CB 128            // stream blocks for count/bin
#define EPB 12500         // NE / CB exactly
#define GEMM_BLOCKS 1563  // ceil(NN/ROWS)

__device__ __forceinline__ uint32_t f2bf(float f) {   // RNE to bf16 bits
    uint32_t u = __float_as_uint(f);
    u += 0x7FFFu + ((u >> 16) & 1u);
    return u >> 16;
}

// ---------------- init: inverse perm + zero summaries -------------------------
__global__ __launch_bounds__(256) void init_k(const int* __restrict__ perm,
                                              int* __restrict__ invp,
                                              float* __restrict__ summ)
{
    int i = blockIdx.x * 256 + threadIdx.x;
    int r = blockIdx.y;
    if (i < NN) invp[r * NN + perm[r * NN + i]] = i;
    if (r == 0 && blockIdx.x == 0 && i < NR * FOUT) summ[i] = 0.0f;
}

// ---------------- pass 1: per-(block,bucket) histogram (LDS atomics only) -----
__global__ __launch_bounds__(256) void cnt_k(const int* __restrict__ eid,
                                             int* __restrict__ counts)
{
    __shared__ int hist[NB];
    for (int j = threadIdx.x; j < NB; j += 256) hist[j] = 0;
    __syncthreads();
    const int base = blockIdx.x * EPB;
    for (int t = threadIdx.x; t < EPB; t += 256)
        atomicAdd(&hist[eid[base + t] >> BSH], 1);
    __syncthreads();
    for (int j = threadIdx.x; j < NB; j += 256)
        counts[blockIdx.x * NB + j] = hist[j];
}

// ---------------- pass 2: per-bucket exclusive scan over the 128 blocks -------
__global__ __launch_bounds__(128) void scan_k(const int* __restrict__ counts,
                                              int* __restrict__ bases,
                                              int* __restrict__ bcnt)
{
    const int b = blockIdx.x, t = threadIdx.x;
    __shared__ int sc[CB];
    int v = counts[t * NB + b];
    sc[t] = v;
    __syncthreads();
    for (int off = 1; off < CB; off <<= 1) {
        int u = (t >= off) ? sc[t - off] : 0;
        __syncthreads();
        sc[t] += u;
        __syncthreads();
    }
    bases[t * NB + b] = b * CAP + (sc[t] - v);
    if (t == CB - 1) bcnt[b] = sc[t];
}

// ---------------- pass 3: scatter into bucket runs (LDS cursors) --------------
__global__ __launch_bounds__(256) void bin_k(const int* __restrict__ ei,
                                             const int* __restrict__ bases,
                                             uint32_t* __restrict__ recs)
{
    __shared__ int cur[NB];
    for (int j = threadIdx.x; j < NB; j += 256)
        cur[j] = bases[blockIdx.x * NB + j];
    __syncthreads();
    const int base = blockIdx.x * EPB;
    for (int t = threadIdx.x; t < EPB; t += 256) {
        int e = base + t;
        int src = ei[e];
        int dst = ei[NE + e];
        int bkt = dst >> BSH;
        int idx = atomicAdd(&cur[bkt], 1);
        if (idx < (bkt + 1) * CAP)
            recs[idx] = ((uint32_t)(dst & 63) << 16) | (uint32_t)src;
    }
}

// ---------------- pass 4: per-bucket degree count -> dinv table ---------------
__global__ __launch_bounds__(256) void deg_k(const uint32_t* __restrict__ recs,
                                             const int* __restrict__ bcnt,
                                             float* __restrict__ dinv)
{
    __shared__ int dc[64];
    if (threadIdx.x < 64) dc[threadIdx.x] = 0;
    __syncthreads();
    const int b = blockIdx.x;
    const int n = min(bcnt[b], CAP);
    const uint32_t* rp = recs + (size_t)b * CAP;
    for (int t = threadIdx.x; t < n; t += 256)
        atomicAdd(&dc[rp[t] >> 16], 1);
    __syncthreads();
    if (threadIdx.x < 64) {
        int dst = b * 64 + threadIdx.x;
        if (dst < NN) dinv[dst] = rsqrtf((float)dc[threadIdx.x] + 1.0f);
    }
}

// ---------------- gemm: pos/neg masked GEMM -> scaled packed bf16 table -------
// pk[node*64+f] = u32{ hi = bf16(pos msg * dinv[node]), lo = bf16(neg * dinv) }
__global__ __launch_bounds__(256) void gemm_k(const float* __restrict__ x,
                                              const float* __restrict__ pm,
                                              const float* __restrict__ nm,
                                              const float* __restrict__ Wr,
                                              const float* __restrict__ dinv,
                                              const int*   __restrict__ invp_r,
                                              uint32_t* __restrict__ pk)
{
    __shared__ float sW[FIN * FOUT];      // 32 KB
    __shared__ float sAp[ROWS * FIN];     // 16 KB (XOR-swizzled)
    __shared__ float sAn[ROWS * FIN];     // 16 KB
    const int t = threadIdx.x;
    const int row0 = blockIdx.x * ROWS;

    for (int i = t * 4; i < FIN * FOUT; i += 1024)
        *(float4*)&sW[i] = *(const float4*)&Wr[i];

    for (int i = t * 4; i < ROWS * FIN; i += 1024) {
        int rr = i >> 7, cc = i & 127;
        int row = row0 + rr;
        float4 ap = make_float4(0.f, 0.f, 0.f, 0.f), an = ap;
        if (row < NN) {
            size_t g = (size_t)row * FIN + cc;
            float4 xv = *(const float4*)(x + g);
            float4 pv = *(const float4*)(pm + g);
            float4 nv = *(const float4*)(nm + g);
            ap = make_float4(xv.x * pv.x, xv.y * pv.y, xv.z * pv.z, xv.w * pv.w);
            an = make_float4(xv.x * nv.x, xv.y * nv.y, xv.z * nv.z, xv.w * nv.w);
        }
        int sidx = (rr << 7) + (cc ^ ((rr & 7) << 2));
        *(float4*)&sAp[sidx] = ap;
        *(float4*)&sAn[sidx] = an;
    }
    __syncthreads();

    const int tr = (t >> 4) * 2;
    const int tc = (t & 15) * 4;
    float accp[2][4] = {{0.f,0.f,0.f,0.f},{0.f,0.f,0.f,0.f}};
    float accn[2][4] = {{0.f,0.f,0.f,0.f},{0.f,0.f,0.f,0.f}};

    #pragma unroll 4
    for (int k = 0; k < FIN; k += 4) {
        float4 p0 = *(const float4*)&sAp[((tr    ) << 7) + (k ^ (((tr    ) & 7) << 2))];
        float4 p1 = *(const float4*)&sAp[((tr + 1) << 7) + (k ^ (((tr + 1) & 7) << 2))];
        float4 n0 = *(const float4*)&sAn[((tr    ) << 7) + (k ^ (((tr    ) & 7) << 2))];
        float4 n1 = *(const float4*)&sAn[((tr + 1) << 7) + (k ^ (((tr + 1) & 7) << 2))];
        float ap0[4] = {p0.x, p0.y, p0.z, p0.w};
        float ap1[4] = {p1.x, p1.y, p1.z, p1.w};
        float an0[4] = {n0.x, n0.y, n0.z, n0.w};
        float an1[4] = {n1.x, n1.y, n1.z, n1.w};
        #pragma unroll
        for (int j = 0; j < 4; ++j) {
            float4 wv = *(const float4*)&sW[(k + j) * FOUT + tc];
            float wj[4] = {wv.x, wv.y, wv.z, wv.w};
            #pragma unroll
            for (int c = 0; c < 4; ++c) {
                accp[0][c] += ap0[j] * wj[c];
                accp[1][c] += ap1[j] * wj[c];
                accn[0][c] += an0[j] * wj[c];
                accn[1][c] += an1[j] * wj[c];
            }
        }
    }

    #pragma unroll
    for (int rr = 0; rr < 2; ++rr) {
        int row = row0 + tr + rr;
        if (row >= NN) continue;
        float dp = dinv[row];
        int ni = invp_r[row];
        float dn = dinv[ni];
        #pragma unroll
        for (int c = 0; c < 4; ++c) {
            ((uint16_t*)&pk[(size_t)row * 64 + tc + c])[1] = (uint16_t)f2bf(accp[rr][c] * dp);
            ((uint16_t*)&pk[(size_t)ni  * 64 + tc + c])[0] = (uint16_t)f2bf(accn[rr][c] * dn);
        }
    }
}

// ---------------- agg: one block per bucket, LDS f32 accumulators -------------
__global__ __launch_bounds__(256) void agg_k(const uint32_t* __restrict__ recs,
                                             const int* __restrict__ bcnt,
                                             const uint32_t* __restrict__ pk,
                                             const float* __restrict__ dinv,
                                             const float* __restrict__ br,
                                             float* __restrict__ outp,
                                             float* __restrict__ outn,
                                             float* __restrict__ summ)
{
    __shared__ float acc[64][2][64];    // 32 KB
    for (int i = threadIdx.x; i < 64 * 2 * 64; i += 256)
        ((float*)acc)[i] = 0.f;
    __syncthreads();

    const int b = blockIdx.x;
    const int n = min(bcnt[b], CAP);
    const uint32_t* rp = recs + (size_t)b * CAP;
    const int lane = threadIdx.x & 63;
    const int w = threadIdx.x >> 6;

    int lo = (n * w) >> 2;
    int hi = (n * (w + 1)) >> 2;
    int t = lo;
    for (; t + 4 <= hi; t += 4) {
        uint32_t r0 = rp[t], r1 = rp[t+1], r2 = rp[t+2], r3 = rp[t+3];
        uint32_t g0 = pk[(size_t)(r0 & 0xFFFF) * 64 + lane];
        uint32_t g1 = pk[(size_t)(r1 & 0xFFFF) * 64 + lane];
        uint32_t g2 = pk[(size_t)(r2 & 0xFFFF) * 64 + lane];
        uint32_t g3 = pk[(size_t)(r3 & 0xFFFF) * 64 + lane];
        int d0 = r0 >> 16, d1 = r1 >> 16, d2 = r2 >> 16, d3 = r3 >> 16;
        atomicAdd(&acc[d0][0][lane], __uint_as_float(g0 & 0xFFFF0000u));
        atomicAdd(&acc[d0][1][lane], __uint_as_float(g0 << 16));
        atomicAdd(&acc[d1][0][lane], __uint_as_float(g1 & 0xFFFF0000u));
        atomicAdd(&acc[d1][1][lane], __uint_as_float(g1 << 16));
        atomicAdd(&acc[d2][0][lane], __uint_as_float(g2 & 0xFFFF0000u));
        atomicAdd(&acc[d2][1][lane], __uint_as_float(g2 << 16));
        atomicAdd(&acc[d3][0][lane], __uint_as_float(g3 & 0xFFFF0000u));
        atomicAdd(&acc[d3][1][lane], __uint_as_float(g3 << 16));
    }
    for (; t < hi; ++t) {
        uint32_t r = rp[t];
        uint32_t g = pk[(size_t)(r & 0xFFFF) * 64 + lane];
        int dl = r >> 16;
        atomicAdd(&acc[dl][0][lane], __uint_as_float(g & 0xFFFF0000u));
        atomicAdd(&acc[dl][1][lane], __uint_as_float(g << 16));
    }
    __syncthreads();

    // epilogue: self-loop + bias + relu + store; stash pos out for summary
    for (int idx = threadIdx.x; idx < 64 * 64; idx += 256) {
        int dl = idx >> 6, f = idx & 63;
        int dst = b * 64 + dl;
        float op = 0.f;
        if (dst < NN) {
            uint32_t gs = pk[(size_t)dst * 64 + f];
            float dv = dinv[dst];
            float bf = br[f];
            op = fmaxf(fmaf(dv, acc[dl][0][f] + __uint_as_float(gs & 0xFFFF0000u), bf), 0.f);
            float on = fmaxf(fmaf(dv, acc[dl][1][f] + __uint_as_float(gs << 16), bf), 0.f);
            outp[(size_t)dst * FOUT + f] = op;
            outn[(size_t)dst * FOUT + f] = on;
        }
        acc[dl][0][f] = op;
    }
    __syncthreads();
    if (threadIdx.x < 64) {
        float s = 0.f;
        #pragma unroll
        for (int dl = 0; dl < 64; ++dl) s += acc[dl][0][threadIdx.x];
        atomicAdd(&summ[threadIdx.x], s * (1.0f / NN));
    }
}

extern "C" void kernel_launch(void* const* d_in, const int* in_sizes, int n_in,
                              void* d_out, int out_size, void* d_ws, size_t ws_size,
                              hipStream_t stream)
{
    const float* x    = (const float*)d_in[0];
    const int*   ei   = (const int*)  d_in[1];
    const float* W    = (const float*)d_in[2];
    const float* b    = (const float*)d_in[3];
    const float* pm   = (const float*)d_in[4];
    const float* nm   = (const float*)d_in[5];
    const int*   perm = (const int*)  d_in[6];
    float* out = (float*)d_out;

    // ws: invp[R*N] i32 | counts[CB*NB] | bases[CB*NB] | bcnt[NB]
    //   | recs[NB*CAP] u32 | dinv[NN] f32 | pk[NN*64] u32     (~27.5 MB)
    int*      invp   = (int*)d_ws;
    int*      counts = invp + (size_t)NR * NN;
    int*      bases  = counts + (size_t)CB * NB;
    int*      bcnt   = bases + (size_t)CB * NB;
    uint32_t* recs   = (uint32_t*)(bcnt + NB);
    float*    dinv   = (float*)(recs + (size_t)NB * CAP);
    uint32_t* pk     = (uint32_t*)(dinv + NN);

    const size_t NF = (size_t)NN * FOUT;
    float* outp0 = out;
    float* outn0 = out + (size_t)NR * NF;
    float* summ  = out + 2 * (size_t)NR * NF;

    init_k<<<dim3((NN + 255) / 256, NR), 256, 0, stream>>>(perm, invp, summ);

    for (int r = 0; r < NR; ++r) {
        const int* ei_r = ei + (size_t)r * 2 * NE;
        cnt_k <<<dim3(CB), 256, 0, stream>>>(ei_r + NE, counts);
        scan_k<<<dim3(NB), 128, 0, stream>>>(counts, bases, bcnt);
        bin_k <<<dim3(CB), 256, 0, stream>>>(ei_r, bases, recs);
        deg_k <<<dim3(NB), 256, 0, stream>>>(recs, bcnt, dinv);
        gemm_k<<<dim3(GEMM_BLOCKS), 256, 0, stream>>>(
            x, pm + (size_t)r * NN * FIN, nm + (size_t)r * NN * FIN,
            W + (size_t)r * FIN * FOUT, dinv, invp + (size_t)r * NN, pk);
        agg_k <<<dim3(NB), 256, 0, stream>>>(
            recs, bcnt, pk, dinv, b + (size_t)r * FOUT,
            outp0 + r * NF, outn0 + r * NF, summ + r * FOUT);
    }
}

// Round 12
// 1040.421 us; speedup vs baseline: 5.6926x; 5.6926x over previous
//
#include <hip/hip_runtime.h>
#include <stdint.h>

#define NN 50000
#define NE 1600000
#define FIN 128
#define FOUT 64
#define NR 4
#define ROWS 32
#define BSH 6
#define NB 782            // ceil(NN/64) buckets of 64 dsts
#define CAP 4096          // bucket capacity (mean 2048, Poisson, >40 sigma)
#define CB 128            // stream blocks for count/bin
#define EPB 12500         // NE / CB exactly
#define GEMM_BLOCKS 1563  // ceil(NN/ROWS)
#define AGG_BLOCKS 3125   // x4 waves = 12500 waves, one dst per wave

__device__ __forceinline__ uint32_t f2bf(float f) {   // RNE to bf16 bits
    uint32_t u = __float_as_uint(f);
    u += 0x7FFFu + ((u >> 16) & 1u);
    return u >> 16;
}

// ---------------- init: inverse perm + zero summaries -------------------------
__global__ __launch_bounds__(256) void init_k(const int* __restrict__ perm,
                                              int* __restrict__ invp,
                                              float* __restrict__ summ)
{
    int i = blockIdx.x * 256 + threadIdx.x;
    int r = blockIdx.y;
    if (i < NN) invp[r * NN + perm[r * NN + i]] = i;
    if (r == 0 && blockIdx.x == 0 && i < NR * FOUT) summ[i] = 0.0f;
}

// ---------------- pass 1: per-(block,bucket) histogram (LDS atomics only) -----
__global__ __launch_bounds__(256) void cnt_k(const int* __restrict__ eid,
                                             int* __restrict__ counts)
{
    __shared__ int hist[NB];
    for (int j = threadIdx.x; j < NB; j += 256) hist[j] = 0;
    __syncthreads();
    const int base = blockIdx.x * EPB;
    for (int t = threadIdx.x; t < EPB; t += 256)
        atomicAdd(&hist[eid[base + t] >> BSH], 1);
    __syncthreads();
    for (int j = threadIdx.x; j < NB; j += 256)
        counts[blockIdx.x * NB + j] = hist[j];
}

// ---------------- pass 2: per-bucket exclusive scan over the 128 blocks -------
__global__ __launch_bounds__(128) void scan_k(const int* __restrict__ counts,
                                              int* __restrict__ bases,
                                              int* __restrict__ bcnt)
{
    const int b = blockIdx.x, t = threadIdx.x;
    __shared__ int sc[CB];
    int v = counts[t * NB + b];
    sc[t] = v;
    __syncthreads();
    for (int off = 1; off < CB; off <<= 1) {
        int u = (t >= off) ? sc[t - off] : 0;
        __syncthreads();
        sc[t] += u;
        __syncthreads();
    }
    bases[t * NB + b] = b * CAP + (sc[t] - v);
    if (t == CB - 1) bcnt[b] = sc[t];
}

// ---------------- pass 3: scatter into bucket runs (LDS cursors) --------------
__global__ __launch_bounds__(256) void bin_k(const int* __restrict__ ei,
                                             const int* __restrict__ bases,
                                             uint32_t* __restrict__ recs)
{
    __shared__ int cur[NB];
    for (int j = threadIdx.x; j < NB; j += 256)
        cur[j] = bases[blockIdx.x * NB + j];
    __syncthreads();
    const int base = blockIdx.x * EPB;
    for (int t = threadIdx.x; t < EPB; t += 256) {
        int e = base + t;
        int src = ei[e];
        int dst = ei[NE + e];
        int bkt = dst >> BSH;
        int idx = atomicAdd(&cur[bkt], 1);
        if (idx < (bkt + 1) * CAP)
            recs[idx] = ((uint32_t)(dst & 63) << 16) | (uint32_t)src;
    }
}

// ---------------- pass 4: per-bucket counting sort by dst ---------------------
// emits per-dst contiguous (8-aligned) u16 src runs + dpack = {deg<<24 | start}
__global__ __launch_bounds__(256) void sort_k(const uint32_t* __restrict__ recs,
                                              const int* __restrict__ bcnt,
                                              uint16_t* __restrict__ srt,
                                              uint32_t* __restrict__ dpack)
{
    __shared__ uint32_t sr[CAP];      // 16 KB
    __shared__ int cnt4[4][64];
    __shared__ int start64[64];
    __shared__ int cur4[4][64];
    const int b = blockIdx.x, t = threadIdx.x, w = t >> 6;
    const int n = min(bcnt[b], CAP);

    for (int j = t; j < n; j += 256) sr[j] = recs[(size_t)b * CAP + j];
    cnt4[t >> 6][t & 63] = 0;
    __syncthreads();

    for (int j = t; j < n; j += 256)
        atomicAdd(&cnt4[w][sr[j] >> 16], 1);
    __syncthreads();

    if (t == 0) {
        int acc = 0;
        #pragma unroll 8
        for (int dl = 0; dl < 64; ++dl) {
            int tot = cnt4[0][dl] + cnt4[1][dl] + cnt4[2][dl] + cnt4[3][dl];
            start64[dl] = acc;
            acc += (tot + 7) & ~7;               // 8-pad each run (uint4 loads)
        }
    }
    __syncthreads();

    if (t < 64) {
        int s = start64[t];
        int c0 = cnt4[0][t], c1 = cnt4[1][t], c2 = cnt4[2][t];
        cur4[0][t] = s;
        cur4[1][t] = s + c0;
        cur4[2][t] = s + c0 + c1;
        cur4[3][t] = s + c0 + c1 + c2;
        int dst = b * 64 + t;
        if (dst < NN) {
            int tot = c0 + c1 + c2 + cnt4[3][t];
            dpack[dst] = ((uint32_t)min(tot, 255) << 24) |
                         (uint32_t)(b * CAP + s);
        }
    }
    __syncthreads();

    for (int j = t; j < n; j += 256) {
        uint32_t r = sr[j];
        int dl = r >> 16;
        int idx = atomicAdd(&cur4[w][dl], 1);
        if (idx < CAP) srt[(size_t)b * CAP + idx] = (uint16_t)(r & 0xFFFF);
    }
}

// ---------------- gemm: pos/neg masked GEMM -> SCALED packed bf16 table -------
// pk[node*64+f] = u32{ hi = bf16(pos*dinv[node]), lo = bf16(neg*dinv[node]) }
__global__ __launch_bounds__(256) void gemm_k(const float* __restrict__ x,
                                              const float* __restrict__ pm,
                                              const float* __restrict__ nm,
                                              const float* __restrict__ Wr,
                                              const uint32_t* __restrict__ dpack,
                                              const int*   __restrict__ invp_r,
                                              uint32_t* __restrict__ pk)
{
    __shared__ float sW[FIN * FOUT];      // 32 KB
    __shared__ float sAp[ROWS * FIN];     // 16 KB (XOR-swizzled)
    __shared__ float sAn[ROWS * FIN];     // 16 KB
    const int t = threadIdx.x;
    const int row0 = blockIdx.x * ROWS;

    for (int i = t * 4; i < FIN * FOUT; i += 1024)
        *(float4*)&sW[i] = *(const float4*)&Wr[i];

    for (int i = t * 4; i < ROWS * FIN; i += 1024) {
        int rr = i >> 7, cc = i & 127;
        int row = row0 + rr;
        float4 ap = make_float4(0.f, 0.f, 0.f, 0.f), an = ap;
        if (row < NN) {
            size_t g = (size_t)row * FIN + cc;
            float4 xv = *(const float4*)(x + g);
            float4 pv = *(const float4*)(pm + g);
            float4 nv = *(const float4*)(nm + g);
            ap = make_float4(xv.x * pv.x, xv.y * pv.y, xv.z * pv.z, xv.w * pv.w);
            an = make_float4(xv.x * nv.x, xv.y * nv.y, xv.z * nv.z, xv.w * nv.w);
        }
        int sidx = (rr << 7) + (cc ^ ((rr & 7) << 2));
        *(float4*)&sAp[sidx] = ap;
        *(float4*)&sAn[sidx] = an;
    }
    __syncthreads();

    const int tr = (t >> 4) * 2;
    const int tc = (t & 15) * 4;
    float accp[2][4] = {{0.f,0.f,0.f,0.f},{0.f,0.f,0.f,0.f}};
    float accn[2][4] = {{0.f,0.f,0.f,0.f},{0.f,0.f,0.f,0.f}};

    #pragma unroll 4
    for (int k = 0; k < FIN; k += 4) {
        float4 p0 = *(const float4*)&sAp[((tr    ) << 7) + (k ^ (((tr    ) & 7) << 2))];
        float4 p1 = *(const float4*)&sAp[((tr + 1) << 7) + (k ^ (((tr + 1) & 7) << 2))];
        float4 n0 = *(const float4*)&sAn[((tr    ) << 7) + (k ^ (((tr    ) & 7) << 2))];
        float4 n1 = *(const float4*)&sAn[((tr + 1) << 7) + (k ^ (((tr + 1) & 7) << 2))];
        float ap0[4] = {p0.x, p0.y, p0.z, p0.w};
        float ap1[4] = {p1.x, p1.y, p1.z, p1.w};
        float an0[4] = {n0.x, n0.y, n0.z, n0.w};
        float an1[4] = {n1.x, n1.y, n1.z, n1.w};
        #pragma unroll
        for (int j = 0; j < 4; ++j) {
            float4 wv = *(const float4*)&sW[(k + j) * FOUT + tc];
            float wj[4] = {wv.x, wv.y, wv.z, wv.w};
            #pragma unroll
            for (int c = 0; c < 4; ++c) {
                accp[0][c] += ap0[j] * wj[c];
                accp[1][c] += ap1[j] * wj[c];
                accn[0][c] += an0[j] * wj[c];
                accn[1][c] += an1[j] * wj[c];
            }
        }
    }

    #pragma unroll
    for (int rr = 0; rr < 2; ++rr) {
        int row = row0 + tr + rr;
        if (row >= NN) continue;
        float dp = rsqrtf((float)(dpack[row] >> 24) + 1.0f);
        int ni = invp_r[row];
        float dn = rsqrtf((float)(dpack[ni] >> 24) + 1.0f);
        #pragma unroll
        for (int c = 0; c < 4; ++c) {
            ((uint16_t*)&pk[(size_t)row * 64 + tc + c])[1] = (uint16_t)f2bf(accp[rr][c] * dp);
            ((uint16_t*)&pk[(size_t)ni  * 64 + tc + c])[0] = (uint16_t)f2bf(accn[rr][c] * dn);
        }
    }
}

// ---------------- agg: one wave per dst, contiguous CSR run, register acc -----
__global__ __launch_bounds__(256) void agg_k(const uint32_t* __restrict__ dpack,
                                             const uint16_t* __restrict__ srt,
                                             const uint32_t* __restrict__ pk,
                                             const float* __restrict__ br,
                                             float* __restrict__ outp,
                                             float* __restrict__ outn,
                                             float* __restrict__ summ)
{
    const int lane = threadIdx.x & 63;
    const int w0 = blockIdx.x * 4 + (threadIdx.x >> 6);
    const float bl = br[lane];
    float part = 0.f;

    for (int dst = w0; dst < NN; dst += 4 * AGG_BLOCKS) {
        uint32_t pc = dpack[dst];
        int deg = (int)(pc >> 24);
        const uint16_t* row = srt + (pc & 0xFFFFFFu);
        uint32_t gs = pk[(size_t)dst * 64 + lane];          // self-loop (scaled)
        float accp = __uint_as_float(gs & 0xFFFF0000u);
        float accn = __uint_as_float(gs << 16);
        int j = 0;
        for (; j + 8 <= deg; j += 8) {
            uint4 rv = *(const uint4*)(row + j);
            int s0 = rv.x & 0xFFFF, s1 = (int)(rv.x >> 16);
            int s2 = rv.y & 0xFFFF, s3 = (int)(rv.y >> 16);
            int s4 = rv.z & 0xFFFF, s5 = (int)(rv.z >> 16);
            int s6 = rv.w & 0xFFFF, s7 = (int)(rv.w >> 16);
            uint32_t g0 = pk[(size_t)s0*64+lane], g1 = pk[(size_t)s1*64+lane];
            uint32_t g2 = pk[(size_t)s2*64+lane], g3 = pk[(size_t)s3*64+lane];
            uint32_t g4 = pk[(size_t)s4*64+lane], g5 = pk[(size_t)s5*64+lane];
            uint32_t g6 = pk[(size_t)s6*64+lane], g7 = pk[(size_t)s7*64+lane];
            accp += __uint_as_float(g0 & 0xFFFF0000u) + __uint_as_float(g1 & 0xFFFF0000u)
                  + __uint_as_float(g2 & 0xFFFF0000u) + __uint_as_float(g3 & 0xFFFF0000u)
                  + __uint_as_float(g4 & 0xFFFF0000u) + __uint_as_float(g5 & 0xFFFF0000u)
                  + __uint_as_float(g6 & 0xFFFF0000u) + __uint_as_float(g7 & 0xFFFF0000u);
            accn += __uint_as_float(g0 << 16) + __uint_as_float(g1 << 16)
                  + __uint_as_float(g2 << 16) + __uint_as_float(g3 << 16)
                  + __uint_as_float(g4 << 16) + __uint_as_float(g5 << 16)
                  + __uint_as_float(g6 << 16) + __uint_as_float(g7 << 16);
        }
        for (; j < deg; ++j) {
            uint32_t g = pk[(size_t)row[j] * 64 + lane];
            accp += __uint_as_float(g & 0xFFFF0000u);
            accn += __uint_as_float(g << 16);
        }
        float d = rsqrtf((float)deg + 1.0f);
        float op = fmaxf(fmaf(d, accp, bl), 0.f);
        float on = fmaxf(fmaf(d, accn, bl), 0.f);
        outp[(size_t)dst * FOUT + lane] = op;
        outn[(size_t)dst * FOUT + lane] = on;
        part += op;
    }

    __shared__ float red[256];
    red[threadIdx.x] = part;
    __syncthreads();
    if (threadIdx.x < 64) {
        float s = red[threadIdx.x] + red[threadIdx.x + 64] +
                  red[threadIdx.x + 128] + red[threadIdx.x + 192];
        atomicAdd(&summ[threadIdx.x], s * (1.0f / NN));
    }
}

extern "C" void kernel_launch(void* const* d_in, const int* in_sizes, int n_in,
                              void* d_out, int out_size, void* d_ws, size_t ws_size,
                              hipStream_t stream)
{
    const float* x    = (const float*)d_in[0];
    const int*   ei   = (const int*)  d_in[1];
    const float* W    = (const float*)d_in[2];
    const float* b    = (const float*)d_in[3];
    const float* pm   = (const float*)d_in[4];
    const float* nm   = (const float*)d_in[5];
    const int*   perm = (const int*)  d_in[6];
    float* out = (float*)d_out;

    // ws: invp[R*N] | counts[CB*NB] | bases[CB*NB] | bcnt[800 pad] | recs[NB*CAP] u32
    //   | srt[NB*CAP] u16 | dpack[NN] u32 | pk[NN*64] u32          (~34 MB)
    int*      invp   = (int*)d_ws;
    int*      counts = invp + (size_t)NR * NN;
    int*      bases  = counts + (size_t)CB * NB;
    int*      bcnt   = bases + (size_t)CB * NB;
    uint32_t* recs   = (uint32_t*)(bcnt + 800);
    uint16_t* srt    = (uint16_t*)(recs + (size_t)NB * CAP);
    uint32_t* dpack  = (uint32_t*)(srt + (size_t)NB * CAP);
    uint32_t* pk     = dpack + NN;

    const size_t NF = (size_t)NN * FOUT;
    float* outp0 = out;
    float* outn0 = out + (size_t)NR * NF;
    float* summ  = out + 2 * (size_t)NR * NF;

    init_k<<<dim3((NN + 255) / 256, NR), 256, 0, stream>>>(perm, invp, summ);

    for (int r = 0; r < NR; ++r) {
        const int* ei_r = ei + (size_t)r * 2 * NE;
        cnt_k <<<dim3(CB), 256, 0, stream>>>(ei_r + NE, counts);
        scan_k<<<dim3(NB), 128, 0, stream>>>(counts, bases, bcnt);
        bin_k <<<dim3(CB), 256, 0, stream>>>(ei_r, bases, recs);
        sort_k<<<dim3(NB), 256, 0, stream>>>(recs, bcnt, srt, dpack);
        gemm_k<<<dim3(GEMM_BLOCKS), 256, 0, stream>>>(
            x, pm + (size_t)r * NN * FIN, nm + (size_t)r * NN * FIN,
            W + (size_t)r * FIN * FOUT, dpack, invp + (size_t)r * NN, pk);
        agg_k <<<dim3(AGG_BLOCKS), 256, 0, stream>>>(
            dpack, srt, pk, b + (size_t)r * FOUT,
            outp0 + r * NF, outn0 + r * NF, summ + r * FOUT);
    }
}